// Round 1
// baseline (688.475 us; speedup 1.0000x reference)
//
#include <hip/hip_runtime.h>
#include <stdint.h>

// Problem constants
#define N_ROWS 16384   // 16*1024 flattened input rows
#define N_EMB  8192    // codebook size
#define C_DIM  256     // embedding dim
#define KCAT   768     // concatenated K for bf16x3 fp32-emulation GEMM

// d_out layout (float element offsets), outputs concatenated in return order:
// loss(1), quantized_st(16*1024*3*256), perplexity(1), encoding_indices(16384*3), distances(16384*8192)
#define OFF_LOSS 0ull
#define OFF_Q    1ull
#define OFF_PERP 12582913ull
#define OFF_IDX  12582914ull
#define OFF_DIST 12632066ull

typedef short bf16x8 __attribute__((ext_vector_type(8)));
typedef float f32x4  __attribute__((ext_vector_type(4)));

// ---------------- prep: fp32 -> bf16 hi/lo concat + row norms ----------------
__device__ __forceinline__ unsigned short f2bf_rne(float f){
  unsigned u = __float_as_uint(f);
  unsigned r = 0x7fffu + ((u >> 16) & 1u);
  return (unsigned short)((u + r) >> 16);
}

__global__ __launch_bounds__(256) void k_prep(
    const float* __restrict__ X, const float* __restrict__ E,
    short* __restrict__ Xc, short* __restrict__ Ec,
    float* __restrict__ xnorm, float* __restrict__ enorm)
{
  int b = blockIdx.x; int t = threadIdx.x;
  const float* src; short* dst; float* nrm; int row; bool isX;
  if (b < N_ROWS){ row = b;          src = X; dst = Xc; nrm = xnorm; isX = true;  }
  else           { row = b - N_ROWS; src = E; dst = Ec; nrm = enorm; isX = false; }
  float x = src[(size_t)row * C_DIM + t];
  unsigned short hi = f2bf_rne(x);
  float hf = __uint_as_float((unsigned)hi << 16);
  unsigned short lo = f2bf_rne(x - hf);
  size_t base = (size_t)row * KCAT;
  if (isX){ // X_cat = [hi, lo, hi]
    dst[base + t] = (short)hi; dst[base + 256 + t] = (short)lo; dst[base + 512 + t] = (short)hi;
  } else {  // E_cat = [hi, hi, lo]
    dst[base + t] = (short)hi; dst[base + 256 + t] = (short)hi; dst[base + 512 + t] = (short)lo;
  }
  float s = x * x;
  #pragma unroll
  for (int off = 32; off > 0; off >>= 1) s += __shfl_down(s, off);
  __shared__ float w4[4];
  int lane = t & 63, wid = t >> 6;
  if (lane == 0) w4[wid] = s;
  __syncthreads();
  if (t == 0) nrm[row] = w4[0] + w4[1] + w4[2] + w4[3];
}

// ---------------- GEMM: distances = xnorm + enorm - 2 * Xc @ Ec^T ----------------
__device__ __forceinline__ void gload16(void* lds, const void* g){
  __builtin_amdgcn_global_load_lds(
      (const __attribute__((address_space(1))) void*)g,
      (__attribute__((address_space(3))) void*)lds, 16, 0, 0);
}

__global__ __launch_bounds__(256) void k_gemm(
    const short* __restrict__ Xc, const short* __restrict__ Ec,
    const float* __restrict__ xnorm, const float* __restrict__ enorm,
    float* __restrict__ out)
{
  __shared__ __align__(16) short As[128 * 64];
  __shared__ __align__(16) short Bs[128 * 64];
  int tid = threadIdx.x;
  int lane = tid & 63, w = tid >> 6;
  int wr = w >> 1, wc = w & 1;          // 2x2 wave grid, each wave: 64x64 out
  int bm = blockIdx.y, bn = blockIdx.x; // 128x64 grid of 128x128 tiles

  f32x4 acc[4][4];
  #pragma unroll
  for (int m = 0; m < 4; m++)
    #pragma unroll
    for (int n = 0; n < 4; n++) acc[m][n] = (f32x4){0.f, 0.f, 0.f, 0.f};

  int lr  = lane >> 3;  // row within 8-row staging chunk
  int lc8 = lane & 7;   // 16B chunk within 128B row
  const short* gA = Xc + (size_t)(bm * 128 + w * 8 + lr) * KCAT + lc8 * 8;
  const short* gB = Ec + (size_t)(bn * 128 + w * 8 + lr) * KCAT + lc8 * 8;
  short* lA = &As[(w * 8) * 64]; // wave-uniform LDS base; HW adds lane*16B
  short* lB = &Bs[(w * 8) * 64];

  for (int kt = 0; kt < 12; ++kt){
    int kk = kt * 64;
    #pragma unroll
    for (int p = 0; p < 4; p++){
      gload16(lA + p * 32 * 64, gA + (size_t)p * 32 * KCAT + kk);
      gload16(lB + p * 32 * 64, gB + (size_t)p * 32 * KCAT + kk);
    }
    __syncthreads();
    #pragma unroll
    for (int ks = 0; ks < 64; ks += 32){
      bf16x8 af[4], bf[4];
      #pragma unroll
      for (int m = 0; m < 4; m++)
        af[m] = *(const bf16x8*)&As[(wr * 64 + m * 16 + (lane & 15)) * 64 + ks + (lane >> 4) * 8];
      #pragma unroll
      for (int n = 0; n < 4; n++)
        bf[n] = *(const bf16x8*)&Bs[(wc * 64 + n * 16 + (lane & 15)) * 64 + ks + (lane >> 4) * 8];
      #pragma unroll
      for (int m = 0; m < 4; m++)
        #pragma unroll
        for (int n = 0; n < 4; n++)
          acc[m][n] = __builtin_amdgcn_mfma_f32_16x16x32_bf16(af[m], bf[n], acc[m][n], 0, 0, 0);
    }
    __syncthreads();
  }

  // epilogue: dist = ||x||^2 + ||e||^2 - 2*dot  (C/D map: col=lane&15, row=(lane>>4)*4+j)
  int lg = lane >> 4, lc = lane & 15;
  float xn[4][4];
  #pragma unroll
  for (int m = 0; m < 4; m++){
    int rb = bm * 128 + wr * 64 + m * 16 + lg * 4;
    #pragma unroll
    for (int j = 0; j < 4; j++) xn[m][j] = xnorm[rb + j];
  }
  #pragma unroll
  for (int n = 0; n < 4; n++){
    int col = bn * 128 + wc * 64 + n * 16 + lc;
    float en = enorm[col];
    #pragma unroll
    for (int m = 0; m < 4; m++){
      int rb = bm * 128 + wr * 64 + m * 16 + lg * 4;
      #pragma unroll
      for (int j = 0; j < 4; j++){
        float d = xn[m][j] + en - 2.0f * acc[m][n][j];
        out[OFF_DIST + (size_t)(rb + j) * N_EMB + col] = d;
      }
    }
  }
}

// ---------------- top-3 per row (tie-break: lower index, = jax.lax.top_k) ----------------
#define LT(av,ai,bv,bi) (((av) < (bv)) || ((av) == (bv) && (ai) < (bi)))

__global__ __launch_bounds__(256) void k_topk(
    float* out, int* __restrict__ top_idx, int* __restrict__ counts)
{
  int row = blockIdx.x; int tid = threadIdx.x;
  const float* drow = out + OFF_DIST + (size_t)row * N_EMB;
  float v0 = __builtin_inff(), v1 = __builtin_inff(), v2 = __builtin_inff();
  int   i0 = 0x7fffffff,       i1 = 0x7fffffff,       i2 = 0x7fffffff;
  for (int i = tid; i < N_EMB; i += 256){
    float d = drow[i];
    if (LT(d, i, v2, i2)){
      if (LT(d, i, v1, i1)){
        v2 = v1; i2 = i1;
        if (LT(d, i, v0, i0)){ v1 = v0; i1 = i0; v0 = d; i0 = i; }
        else                 { v1 = d;  i1 = i; }
      } else { v2 = d; i2 = i; }
    }
  }
  // wave butterfly merge of sorted triples
  #pragma unroll
  for (int off = 1; off < 64; off <<= 1){
    float b0 = __shfl_xor(v0, off), b1 = __shfl_xor(v1, off), b2 = __shfl_xor(v2, off);
    int   j0 = __shfl_xor(i0, off), j1 = __shfl_xor(i1, off), j2 = __shfl_xor(i2, off);
    float a0 = v0, a1 = v1, a2 = v2; int x0 = i0, x1 = i1, x2 = i2;
    float r0, r1, r2; int s0, s1, s2;
    if (LT(a0, x0, b0, j0)){ r0 = a0; s0 = x0; a0 = a1; x0 = x1; a1 = a2; x1 = x2; a2 = __builtin_inff(); x2 = 0x7fffffff; }
    else                   { r0 = b0; s0 = j0; b0 = b1; j0 = j1; b1 = b2; j1 = j2; b2 = __builtin_inff(); j2 = 0x7fffffff; }
    if (LT(a0, x0, b0, j0)){ r1 = a0; s1 = x0; a0 = a1; x0 = x1; a1 = a2; x1 = x2; a2 = __builtin_inff(); x2 = 0x7fffffff; }
    else                   { r1 = b0; s1 = j0; b0 = b1; j0 = j1; b1 = b2; j1 = j2; b2 = __builtin_inff(); j2 = 0x7fffffff; }
    if (LT(a0, x0, b0, j0)){ r2 = a0; s2 = x0; }
    else                   { r2 = b0; s2 = j0; }
    v0 = r0; i0 = s0; v1 = r1; i1 = s1; v2 = r2; i2 = s2;
  }
  __shared__ float swv[4][3]; __shared__ int swi[4][3];
  int lane = tid & 63, wid = tid >> 6;
  if (lane == 0){
    swv[wid][0] = v0; swv[wid][1] = v1; swv[wid][2] = v2;
    swi[wid][0] = i0; swi[wid][1] = i1; swi[wid][2] = i2;
  }
  __syncthreads();
  if (tid == 0){
    for (int wq = 1; wq < 4; wq++){
      for (int t = 0; t < 3; t++){
        float d = swv[wq][t]; int i = swi[wq][t];
        if (LT(d, i, v2, i2)){
          if (LT(d, i, v1, i1)){
            v2 = v1; i2 = i1;
            if (LT(d, i, v0, i0)){ v1 = v0; i1 = i0; v0 = d; i0 = i; }
            else                 { v1 = d;  i1 = i; }
          } else { v2 = d; i2 = i; }
        }
      }
    }
    out[OFF_IDX + (size_t)row * 3 + 0] = (float)i0;
    out[OFF_IDX + (size_t)row * 3 + 1] = (float)i1;
    out[OFF_IDX + (size_t)row * 3 + 2] = (float)i2;
    top_idx[row * 3 + 0] = i0; top_idx[row * 3 + 1] = i1; top_idx[row * 3 + 2] = i2;
    atomicAdd(&counts[i0], 1); atomicAdd(&counts[i1], 1); atomicAdd(&counts[i2], 1);
  }
}

// ---------------- gather + straight-through + loss partials ----------------
__global__ __launch_bounds__(256) void k_quant(
    const float* __restrict__ X, const float* __restrict__ E,
    const int* __restrict__ top_idx, float* __restrict__ out,
    float* __restrict__ partials)
{
  int row = blockIdx.x; int c = threadIdx.x;
  float x = X[(size_t)row * C_DIM + c];
  float lsum = 0.f;
  #pragma unroll
  for (int t = 0; t < 3; t++){
    int idx = top_idx[row * 3 + t];
    float e = E[(size_t)idx * C_DIM + c];
    float diff = e - x;
    out[OFF_Q + ((size_t)row * 3 + t) * C_DIM + c] = x + diff; // literal STE formula
    lsum += diff * diff;
  }
  __shared__ float red[256];
  red[c] = lsum; __syncthreads();
  for (int s = 128; s > 0; s >>= 1){ if (c < s) red[c] += red[c + s]; __syncthreads(); }
  if (c == 0) partials[row] = red[0];
}

// ---------------- scalars: loss + perplexity ----------------
__global__ __launch_bounds__(256) void k_final(
    const float* __restrict__ partials, const int* __restrict__ counts,
    float* __restrict__ out)
{
  int t = threadIdx.x;
  float ls = 0.f;
  for (int i = t; i < N_ROWS; i += 256) ls += partials[i];
  float es = 0.f;
  for (int i = t; i < N_EMB; i += 256){
    float p = (float)counts[i] * (1.0f / 16384.0f);
    es += p * logf(p + 1e-10f);
  }
  __shared__ float r1[256], r2[256];
  r1[t] = ls; r2[t] = es; __syncthreads();
  for (int s = 128; s > 0; s >>= 1){
    if (t < s){ r1[t] += r1[t + s]; r2[t] += r2[t + s]; }
    __syncthreads();
  }
  if (t == 0){
    out[OFF_LOSS] = 0.25f * r1[0] / 12582912.0f;
    out[OFF_PERP] = expf(-r2[0]);
  }
}

extern "C" void kernel_launch(void* const* d_in, const int* in_sizes, int n_in,
                              void* d_out, int out_size, void* d_ws, size_t ws_size,
                              hipStream_t stream)
{
  const float* X = (const float*)d_in[0];
  const float* E = (const float*)d_in[1];
  float* out = (float*)d_out;
  char* ws = (char*)d_ws;
  // ws layout (bytes)
  short* Xc       = (short*)(ws + 0);          // 16384*768*2 = 25165824
  short* Ec       = (short*)(ws + 25165824);   // 8192*768*2  = 12582912
  float* xnorm    = (float*)(ws + 37748736);   // 65536
  float* enorm    = (float*)(ws + 37814272);   // 32768
  int*   top_idx  = (int*)  (ws + 37847040);   // 196608
  int*   counts   = (int*)  (ws + 38043648);   // 32768
  float* partials = (float*)(ws + 38076416);   // 65536  (total ~38.1 MB)

  hipMemsetAsync(counts, 0, N_EMB * sizeof(int), stream);
  k_prep<<<N_ROWS + N_EMB, 256, 0, stream>>>(X, E, Xc, Ec, xnorm, enorm);
  dim3 g(N_EMB / 128, N_ROWS / 128);
  k_gemm<<<g, 256, 0, stream>>>(Xc, Ec, xnorm, enorm, out);
  k_topk<<<N_ROWS, 256, 0, stream>>>(out, top_idx, counts);
  k_quant<<<N_ROWS, 256, 0, stream>>>(X, E, top_idx, out, partials);
  k_final<<<1, 256, 0, stream>>>(partials, counts, out);
}

// Round 2
// 617.399 us; speedup vs baseline: 1.1151x; 1.1151x over previous
//
#include <hip/hip_runtime.h>
#include <stdint.h>

// Problem constants
#define N_ROWS 16384   // 16*1024 flattened input rows
#define N_EMB  8192    // codebook size
#define C_DIM  256     // embedding dim
#define KCAT   768     // concatenated K for bf16x3 fp32-emulation GEMM (12 tiles of 64)

// d_out layout (float element offsets), outputs concatenated in return order:
// loss(1), quantized_st(16*1024*3*256), perplexity(1), encoding_indices(16384*3), distances(16384*8192)
#define OFF_LOSS 0ull
#define OFF_Q    1ull
#define OFF_PERP 12582913ull
#define OFF_IDX  12582914ull
#define OFF_DIST 12632066ull

typedef short bf16x8 __attribute__((ext_vector_type(8)));
typedef float f32x4  __attribute__((ext_vector_type(4)));
typedef float f32x2  __attribute__((ext_vector_type(2)));

// ---------------- prep: fp32 -> bf16 hi/lo, K-chunk-major arranged layout + row norms ----------------
// Arranged layout: element (row, k) lives at dst[ ((k>>3)*NR + row)*8 + (k&7) ]
// i.e. [global_k_chunk][row][8 bf16]. This makes GEMM staging linear/coalesced AND
// LDS reads conflict-free (quarter-wave reads 16 consecutive 16-B slots).
__device__ __forceinline__ unsigned short f2bf_rne(float f){
  unsigned u = __float_as_uint(f);
  unsigned r = 0x7fffu + ((u >> 16) & 1u);
  return (unsigned short)((u + r) >> 16);
}

__global__ __launch_bounds__(256) void k_prep(
    const float* __restrict__ X, const float* __restrict__ E,
    short* __restrict__ XT, short* __restrict__ ET,
    float* __restrict__ xnorm, float* __restrict__ enorm)
{
  int b = blockIdx.x; int t = threadIdx.x;
  const float* src; short* dst; float* nrm; int row, NR; bool isX;
  if (b < N_ROWS){ row = b;          src = X; dst = XT; nrm = xnorm; NR = N_ROWS; isX = true;  }
  else           { row = b - N_ROWS; src = E; dst = ET; nrm = enorm; NR = N_EMB;  isX = false; }
  float x = src[(size_t)row * C_DIM + t];
  unsigned short hi = f2bf_rne(x);
  float hf = __uint_as_float((unsigned)hi << 16);
  unsigned short lo = f2bf_rne(x - hf);

  // X_cat = [hi, lo, hi] ; E_cat = [hi, hi, lo]  (k-blocks of 256)
  int k0 = t, k1 = t + 256, k2 = t + 512;
  unsigned short v0 = hi;
  unsigned short v1 = isX ? lo : hi;
  unsigned short v2 = isX ? hi : lo;
  dst[((size_t)(k0 >> 3) * NR + row) * 8 + (k0 & 7)] = (short)v0;
  dst[((size_t)(k1 >> 3) * NR + row) * 8 + (k1 & 7)] = (short)v1;
  dst[((size_t)(k2 >> 3) * NR + row) * 8 + (k2 & 7)] = (short)v2;

  float s = x * x;
  #pragma unroll
  for (int off = 32; off > 0; off >>= 1) s += __shfl_down(s, off);
  __shared__ float w4[4];
  int lane = t & 63, wid = t >> 6;
  if (lane == 0) w4[wid] = s;
  __syncthreads();
  if (t == 0) nrm[row] = w4[0] + w4[1] + w4[2] + w4[3];
}

// ---------------- GEMM: distances = xnorm + enorm - 2 * X @ E^T (bf16x3 split, K=768) ----------------
__device__ __forceinline__ void gload16(void* lds, const void* g){
  __builtin_amdgcn_global_load_lds(
      (const __attribute__((address_space(1))) void*)g,
      (__attribute__((address_space(3))) void*)lds, 16, 0, 0);
}

__global__ __launch_bounds__(256) void k_gemm(
    const short* __restrict__ XT, const short* __restrict__ ET,
    const float* __restrict__ xnorm, const float* __restrict__ enorm,
    float* __restrict__ out)
{
  // LDS: [dbuf][q=0..7][row=0..127][8 bf16], 16 KB per matrix per buffer = 64 KB total
  __shared__ __align__(16) short As[2][8 * 128 * 8];
  __shared__ __align__(16) short Bs[2][8 * 128 * 8];
  int tid = threadIdx.x;
  int lane = tid & 63, w = tid >> 6;
  int wr = w >> 1, wc = w & 1;          // 2x2 wave grid, each wave: 64x64 out
  int bm = blockIdx.y, bn = blockIdx.x; // 128x64 grid of 128x128 tiles

  f32x4 acc[4][4];
  #pragma unroll
  for (int m = 0; m < 4; m++)
    #pragma unroll
    for (int n = 0; n < 4; n++) acc[m][n] = (f32x4){0.f, 0.f, 0.f, 0.f};

  // staging: per K-tile, 16 wave-instructions per matrix; wave w does pieces w*4..w*4+3
  // piece p -> q = p>>1, row-half rh = p&1 (64 rows). LDS dest wave-uniform; HW adds lane*16.
  auto stage = [&](int d, int kt){
    #pragma unroll
    for (int i = 0; i < 4; i++){
      int p = w * 4 + i;
      int q = p >> 1, rh = p & 1;
      gload16(&As[d][(q * 128 + rh * 64) * 8],
              XT + ((size_t)(kt * 8 + q) * N_ROWS + (size_t)bm * 128 + rh * 64 + lane) * 8);
      gload16(&Bs[d][(q * 128 + rh * 64) * 8],
              ET + ((size_t)(kt * 8 + q) * N_EMB + (size_t)bn * 128 + rh * 64 + lane) * 8);
    }
  };

  auto compute = [&](int d){
    int r15 = lane & 15, lg = lane >> 4;
    #pragma unroll
    for (int ks8 = 0; ks8 < 8; ks8 += 4){   // two K=32 steps per tile
      int q = ks8 + lg;                     // chunk giving k = q*8 .. q*8+7
      bf16x8 af[4], bf[4];
      #pragma unroll
      for (int m = 0; m < 4; m++)
        af[m] = *(const bf16x8*)&As[d][(q * 128 + wr * 64 + m * 16 + r15) * 8];
      #pragma unroll
      for (int n = 0; n < 4; n++)
        bf[n] = *(const bf16x8*)&Bs[d][(q * 128 + wc * 64 + n * 16 + r15) * 8];
      #pragma unroll
      for (int m = 0; m < 4; m++)
        #pragma unroll
        for (int n = 0; n < 4; n++)
          acc[m][n] = __builtin_amdgcn_mfma_f32_16x16x32_bf16(af[m], bf[n], acc[m][n], 0, 0, 0);
    }
  };

  // minimum 2-phase double-buffered pipeline: stage(next) issued before compute(cur);
  // the single __syncthreads per iter (implicit vmcnt(0)+lgkmcnt(0) drain) is the handoff.
  stage(0, 0);
  __syncthreads();
  int cur = 0;
  for (int kt = 0; kt < 11; ++kt){
    stage(cur ^ 1, kt + 1);
    compute(cur);
    __syncthreads();
    cur ^= 1;
  }
  compute(cur);

  // epilogue: dist = ||x||^2 + ||e||^2 - 2*dot  (C/D map: col=lane&15, row=(lane>>4)*4+j)
  int lg = lane >> 4, lc = lane & 15;
  float xn[4][4];
  #pragma unroll
  for (int m = 0; m < 4; m++){
    int rb = bm * 128 + wr * 64 + m * 16 + lg * 4;
    #pragma unroll
    for (int j = 0; j < 4; j++) xn[m][j] = xnorm[rb + j];
  }
  #pragma unroll
  for (int n = 0; n < 4; n++){
    int col = bn * 128 + wc * 64 + n * 16 + lc;
    float en = enorm[col];
    #pragma unroll
    for (int m = 0; m < 4; m++){
      int rb = bm * 128 + wr * 64 + m * 16 + lg * 4;
      #pragma unroll
      for (int j = 0; j < 4; j++){
        float d = xn[m][j] + en - 2.0f * acc[m][n][j];
        out[OFF_DIST + (size_t)(rb + j) * N_EMB + col] = d;
      }
    }
  }
}

// ---------------- top-3 per row (tie-break: lower index, = jax.lax.top_k) ----------------
#define LT(av,ai,bv,bi) (((av) < (bv)) || ((av) == (bv) && (ai) < (bi)))

__global__ __launch_bounds__(256) void k_topk(
    float* out, int* __restrict__ top_idx, int* __restrict__ counts)
{
  int row = blockIdx.x; int tid = threadIdx.x;
  const f32x2* drow = (const f32x2*)(out + OFF_DIST + (size_t)row * N_EMB);
  float v0 = __builtin_inff(), v1 = __builtin_inff(), v2 = __builtin_inff();
  int   i0 = 0x7fffffff,       i1 = 0x7fffffff,       i2 = 0x7fffffff;
  for (int i = tid; i < N_EMB / 2; i += 256){
    f32x2 dv = drow[i];
    #pragma unroll
    for (int j = 0; j < 2; j++){
      float d = dv[j]; int ii = i * 2 + j;
      if (LT(d, ii, v2, i2)){
        if (LT(d, ii, v1, i1)){
          v2 = v1; i2 = i1;
          if (LT(d, ii, v0, i0)){ v1 = v0; i1 = i0; v0 = d; i0 = ii; }
          else                  { v1 = d;  i1 = ii; }
        } else { v2 = d; i2 = ii; }
      }
    }
  }
  // wave butterfly merge of sorted triples
  #pragma unroll
  for (int off = 1; off < 64; off <<= 1){
    float b0 = __shfl_xor(v0, off), b1 = __shfl_xor(v1, off), b2 = __shfl_xor(v2, off);
    int   j0 = __shfl_xor(i0, off), j1 = __shfl_xor(i1, off), j2 = __shfl_xor(i2, off);
    float a0 = v0, a1 = v1, a2 = v2; int x0 = i0, x1 = i1, x2 = i2;
    float r0, r1, r2; int s0, s1, s2;
    if (LT(a0, x0, b0, j0)){ r0 = a0; s0 = x0; a0 = a1; x0 = x1; a1 = a2; x1 = x2; a2 = __builtin_inff(); x2 = 0x7fffffff; }
    else                   { r0 = b0; s0 = j0; b0 = b1; j0 = j1; b1 = b2; j1 = j2; b2 = __builtin_inff(); j2 = 0x7fffffff; }
    if (LT(a0, x0, b0, j0)){ r1 = a0; s1 = x0; a0 = a1; x0 = x1; a1 = a2; x1 = x2; a2 = __builtin_inff(); x2 = 0x7fffffff; }
    else                   { r1 = b0; s1 = j0; b0 = b1; j0 = j1; b1 = b2; j1 = j2; b2 = __builtin_inff(); j2 = 0x7fffffff; }
    if (LT(a0, x0, b0, j0)){ r2 = a0; s2 = x0; }
    else                   { r2 = b0; s2 = j0; }
    v0 = r0; i0 = s0; v1 = r1; i1 = s1; v2 = r2; i2 = s2;
  }
  __shared__ float swv[4][3]; __shared__ int swi[4][3];
  int lane = tid & 63, wid = tid >> 6;
  if (lane == 0){
    swv[wid][0] = v0; swv[wid][1] = v1; swv[wid][2] = v2;
    swi[wid][0] = i0; swi[wid][1] = i1; swi[wid][2] = i2;
  }
  __syncthreads();
  if (tid == 0){
    for (int wq = 1; wq < 4; wq++){
      for (int t = 0; t < 3; t++){
        float d = swv[wq][t]; int i = swi[wq][t];
        if (LT(d, i, v2, i2)){
          if (LT(d, i, v1, i1)){
            v2 = v1; i2 = i1;
            if (LT(d, i, v0, i0)){ v1 = v0; i1 = i0; v0 = d; i0 = i; }
            else                 { v1 = d;  i1 = i; }
          } else { v2 = d; i2 = i; }
        }
      }
    }
    out[OFF_IDX + (size_t)row * 3 + 0] = (float)i0;
    out[OFF_IDX + (size_t)row * 3 + 1] = (float)i1;
    out[OFF_IDX + (size_t)row * 3 + 2] = (float)i2;
    top_idx[row * 3 + 0] = i0; top_idx[row * 3 + 1] = i1; top_idx[row * 3 + 2] = i2;
    atomicAdd(&counts[i0], 1); atomicAdd(&counts[i1], 1); atomicAdd(&counts[i2], 1);
  }
}

// ---------------- gather + straight-through + loss partials ----------------
__global__ __launch_bounds__(256) void k_quant(
    const float* __restrict__ X, const float* __restrict__ E,
    const int* __restrict__ top_idx, float* __restrict__ out,
    float* __restrict__ partials)
{
  int row = blockIdx.x; int c = threadIdx.x;
  float x = X[(size_t)row * C_DIM + c];
  float lsum = 0.f;
  #pragma unroll
  for (int t = 0; t < 3; t++){
    int idx = top_idx[row * 3 + t];
    float e = E[(size_t)idx * C_DIM + c];
    float diff = e - x;
    out[OFF_Q + ((size_t)row * 3 + t) * C_DIM + c] = x + diff; // literal STE formula
    lsum += diff * diff;
  }
  __shared__ float red[256];
  red[c] = lsum; __syncthreads();
  for (int s = 128; s > 0; s >>= 1){ if (c < s) red[c] += red[c + s]; __syncthreads(); }
  if (c == 0) partials[row] = red[0];
}

// ---------------- scalars: loss + perplexity ----------------
__global__ __launch_bounds__(256) void k_final(
    const float* __restrict__ partials, const int* __restrict__ counts,
    float* __restrict__ out)
{
  int t = threadIdx.x;
  float ls = 0.f;
  for (int i = t; i < N_ROWS; i += 256) ls += partials[i];
  float es = 0.f;
  for (int i = t; i < N_EMB; i += 256){
    float p = (float)counts[i] * (1.0f / 16384.0f);
    es += p * logf(p + 1e-10f);
  }
  __shared__ float r1[256], r2[256];
  r1[t] = ls; r2[t] = es; __syncthreads();
  for (int s = 128; s > 0; s >>= 1){
    if (t < s){ r1[t] += r1[t + s]; r2[t] += r2[t + s]; }
    __syncthreads();
  }
  if (t == 0){
    out[OFF_LOSS] = 0.25f * r1[0] / 12582912.0f;
    out[OFF_PERP] = expf(-r2[0]);
  }
}

extern "C" void kernel_launch(void* const* d_in, const int* in_sizes, int n_in,
                              void* d_out, int out_size, void* d_ws, size_t ws_size,
                              hipStream_t stream)
{
  const float* X = (const float*)d_in[0];
  const float* E = (const float*)d_in[1];
  float* out = (float*)d_out;
  char* ws = (char*)d_ws;
  // ws layout (bytes)
  short* XT       = (short*)(ws + 0);          // 16384*768*2 = 25165824 (K-chunk-major)
  short* ET       = (short*)(ws + 25165824);   // 8192*768*2  = 12582912 (K-chunk-major)
  float* xnorm    = (float*)(ws + 37748736);   // 65536
  float* enorm    = (float*)(ws + 37814272);   // 32768
  int*   top_idx  = (int*)  (ws + 37847040);   // 196608
  int*   counts   = (int*)  (ws + 38043648);   // 32768
  float* partials = (float*)(ws + 38076416);   // 65536  (total ~38.1 MB)

  hipMemsetAsync(counts, 0, N_EMB * sizeof(int), stream);
  k_prep<<<N_ROWS + N_EMB, 256, 0, stream>>>(X, E, XT, ET, xnorm, enorm);
  dim3 g(N_EMB / 128, N_ROWS / 128);
  k_gemm<<<g, 256, 0, stream>>>(XT, ET, xnorm, enorm, out);
  k_topk<<<N_ROWS, 256, 0, stream>>>(out, top_idx, counts);
  k_quant<<<N_ROWS, 256, 0, stream>>>(X, E, top_idx, out, partials);
  k_final<<<1, 256, 0, stream>>>(partials, counts, out);
}

// Round 3
// 612.381 us; speedup vs baseline: 1.1243x; 1.0082x over previous
//
#include <hip/hip_runtime.h>
#include <stdint.h>

// Problem constants
#define N_ROWS 16384   // 16*1024 flattened input rows
#define N_EMB  8192    // codebook size
#define C_DIM  256     // embedding dim
#define KCAT   768     // concatenated K for bf16x3 fp32-emulation GEMM (12 tiles of 64)

// d_out layout (float element offsets), outputs concatenated in return order:
// loss(1), quantized_st(16*1024*3*256), perplexity(1), encoding_indices(16384*3), distances(16384*8192)
#define OFF_LOSS 0ull
#define OFF_Q    1ull
#define OFF_PERP 12582913ull
#define OFF_IDX  12582914ull
#define OFF_DIST 12632066ull

typedef short bf16x8 __attribute__((ext_vector_type(8)));
typedef float f32x4  __attribute__((ext_vector_type(4)));
typedef float f32x2  __attribute__((ext_vector_type(2)));

#define WAITVM24 asm volatile("s_waitcnt vmcnt(24)" ::: "memory")
#define WAITVM12 asm volatile("s_waitcnt vmcnt(12)" ::: "memory")
#define WAITVM0  asm volatile("s_waitcnt vmcnt(0)"  ::: "memory")
#define WAITLGKM0 asm volatile("s_waitcnt lgkmcnt(0)" ::: "memory")

// ---------------- prep: fp32 -> bf16 hi/lo, K-chunk-major arranged layout + row norms ----------------
// Arranged layout: element (row, k) lives at dst[ ((k>>3)*NR + row)*8 + (k&7) ]
// i.e. [global_k_chunk][row][8 bf16]: GEMM staging is linear/coalesced AND
// LDS reads are conflict-free (quarter-wave reads 16 consecutive 16-B slots; 2-way = free).
__device__ __forceinline__ unsigned short f2bf_rne(float f){
  unsigned u = __float_as_uint(f);
  unsigned r = 0x7fffu + ((u >> 16) & 1u);
  return (unsigned short)((u + r) >> 16);
}

__global__ __launch_bounds__(256) void k_prep(
    const float* __restrict__ X, const float* __restrict__ E,
    short* __restrict__ XT, short* __restrict__ ET,
    float* __restrict__ xnorm, float* __restrict__ enorm)
{
  int b = blockIdx.x; int t = threadIdx.x;
  const float* src; short* dst; float* nrm; int row, NR; bool isX;
  if (b < N_ROWS){ row = b;          src = X; dst = XT; nrm = xnorm; NR = N_ROWS; isX = true;  }
  else           { row = b - N_ROWS; src = E; dst = ET; nrm = enorm; NR = N_EMB;  isX = false; }
  float x = src[(size_t)row * C_DIM + t];
  unsigned short hi = f2bf_rne(x);
  float hf = __uint_as_float((unsigned)hi << 16);
  unsigned short lo = f2bf_rne(x - hf);

  // X_cat = [hi, lo, hi] ; E_cat = [hi, hi, lo]  (k-blocks of 256)
  int k0 = t, k1 = t + 256, k2 = t + 512;
  unsigned short v0 = hi;
  unsigned short v1 = isX ? lo : hi;
  unsigned short v2 = isX ? hi : lo;
  dst[((size_t)(k0 >> 3) * NR + row) * 8 + (k0 & 7)] = (short)v0;
  dst[((size_t)(k1 >> 3) * NR + row) * 8 + (k1 & 7)] = (short)v1;
  dst[((size_t)(k2 >> 3) * NR + row) * 8 + (k2 & 7)] = (short)v2;

  float s = x * x;
  #pragma unroll
  for (int off = 32; off > 0; off >>= 1) s += __shfl_down(s, off);
  __shared__ float w4[4];
  int lane = t & 63, wid = t >> 6;
  if (lane == 0) w4[wid] = s;
  __syncthreads();
  if (t == 0) nrm[row] = w4[0] + w4[1] + w4[2] + w4[3];
}

// ---------------- GEMM: distances = xnorm + enorm - 2 * X @ E^T (bf16x3 split, K=768) ----------------
// BM=256 BN=128 BK=64, 4 waves (wave grid 2Mx2N, wave-tile 128x64),
// triple-buffered LDS, 3-deep counted-vmcnt pipeline, raw barriers (no vmcnt(0) drain in loop).
__device__ __forceinline__ void gload16(void* lds, const void* g){
  __builtin_amdgcn_global_load_lds(
      (const __attribute__((address_space(1))) void*)g,
      (__attribute__((address_space(3))) void*)lds, 16, 0, 0);
}

__global__ __launch_bounds__(256, 1) void k_gemm(
    const short* __restrict__ XT, const short* __restrict__ ET,
    const float* __restrict__ xnorm, const float* __restrict__ enorm,
    float* __restrict__ out)
{
  // LDS: [buf][q=0..7][row][8 bf16]; A: 3 x 32 KB, B: 3 x 16 KB = 144 KB total
  __shared__ __align__(16) short As[3][8 * 256 * 8];
  __shared__ __align__(16) short Bs[3][8 * 128 * 8];
  int tid = threadIdx.x;
  int lane = tid & 63, w = tid >> 6;
  int wr = w >> 1, wc = w & 1;          // wave grid 2x2; wave-tile 128 (M) x 64 (N)
  // bijective XCD swizzle: 4096 blocks % 8 == 0
  int id = blockIdx.x;
  int swz = (id & 7) * 512 + (id >> 3);
  int bm = swz >> 6, bn = swz & 63;     // bm in [0,64): 256-row tiles; bn in [0,64): 128-col tiles

  f32x4 acc[8][4];
  #pragma unroll
  for (int m = 0; m < 8; m++)
    #pragma unroll
    for (int n = 0; n < 4; n++) acc[m][n] = (f32x4){0.f, 0.f, 0.f, 0.f};

  // Staging one K-tile = 48 wave-gloads (A: 8q x 4 row-quarters, B: 8q x 2); wave w takes 12.
  auto stage = [&](int buf, int kt){
    #pragma unroll
    for (int i = 0; i < 12; i++){
      int p = w * 12 + i;               // wave-uniform
      if (p < 32){
        int q = p >> 2, qr = p & 3;
        gload16(&As[buf][(q * 256 + qr * 64) * 8],
                XT + ((size_t)(kt * 8 + q) * N_ROWS + (size_t)bm * 256 + qr * 64 + lane) * 8);
      } else {
        int pb = p - 32; int q = pb >> 1, qr = pb & 1;
        gload16(&Bs[buf][(q * 128 + qr * 64) * 8],
                ET + ((size_t)(kt * 8 + q) * N_EMB + (size_t)bn * 128 + qr * 64 + lane) * 8);
      }
    }
  };

  int r15 = lane & 15, lg4 = lane >> 4;

  // prologue: stage tiles 0,1,2 (36 loads/wave in flight)
  stage(0, 0); stage(1, 1); stage(2, 2);

  #pragma unroll
  for (int t = 0; t < 12; ++t){
    const int buf = t % 3;
    // tile t ready: all but newest 24 (=tiles t+1,t+2) landed. Tail: 12, then 0.
    if (t < 10)      { WAITVM24; }
    else if (t == 10){ WAITVM12; }
    else             { WAITVM0;  }
    __builtin_amdgcn_s_barrier();       // barrier 1: every wave's tile-t pieces landed

    bf16x8 af0[8], bf0[4], af1[8], bf1[4];
    {
      int q = 0 * 4 + lg4;
      #pragma unroll
      for (int m = 0; m < 8; m++)
        af0[m] = *(const bf16x8*)&As[buf][(q * 256 + wr * 128 + m * 16 + r15) * 8];
      #pragma unroll
      for (int n = 0; n < 4; n++)
        bf0[n] = *(const bf16x8*)&Bs[buf][(q * 128 + wc * 64 + n * 16 + r15) * 8];
    }
    {
      int q = 1 * 4 + lg4;
      #pragma unroll
      for (int m = 0; m < 8; m++)
        af1[m] = *(const bf16x8*)&As[buf][(q * 256 + wr * 128 + m * 16 + r15) * 8];
      #pragma unroll
      for (int n = 0; n < 4; n++)
        bf1[n] = *(const bf16x8*)&Bs[buf][(q * 128 + wc * 64 + n * 16 + r15) * 8];
    }
    // MFMA cluster 0 (K=0..31) — overlaps the af1/bf1 read latency
    __builtin_amdgcn_s_setprio(1);
    #pragma unroll
    for (int m = 0; m < 8; m++)
      #pragma unroll
      for (int n = 0; n < 4; n++)
        acc[m][n] = __builtin_amdgcn_mfma_f32_16x16x32_bf16(af0[m], bf0[n], acc[m][n], 0, 0, 0);
    __builtin_amdgcn_s_setprio(0);

    WAITLGKM0;                           // all my ds_reads of buf complete
    __builtin_amdgcn_sched_barrier(0);
    __builtin_amdgcn_s_barrier();        // barrier 2: ALL waves done reading buf -> safe to restage
    if (t < 9) stage(buf, t + 3);        // prefetch tile t+3 into the now-dead buffer

    // MFMA cluster 1 (K=32..63) — hides the stage issue
    __builtin_amdgcn_s_setprio(1);
    #pragma unroll
    for (int m = 0; m < 8; m++)
      #pragma unroll
      for (int n = 0; n < 4; n++)
        acc[m][n] = __builtin_amdgcn_mfma_f32_16x16x32_bf16(af1[m], bf1[n], acc[m][n], 0, 0, 0);
    __builtin_amdgcn_s_setprio(0);
  }

  // epilogue: dist = ||x||^2 + ||e||^2 - 2*dot  (C/D map: col=lane&15, row=(lane>>4)*4+j)
  int lc = lane & 15;
  #pragma unroll
  for (int m = 0; m < 8; m++){
    int rb = bm * 256 + wr * 128 + m * 16 + lg4 * 4;
    float xn[4];
    #pragma unroll
    for (int j = 0; j < 4; j++) xn[j] = xnorm[rb + j];
    #pragma unroll
    for (int n = 0; n < 4; n++){
      int col = bn * 128 + wc * 64 + n * 16 + lc;
      float en = enorm[col];
      #pragma unroll
      for (int j = 0; j < 4; j++){
        float d = xn[j] + en - 2.0f * acc[m][n][j];
        out[OFF_DIST + (size_t)(rb + j) * N_EMB + col] = d;
      }
    }
  }
}

// ---------------- top-3 per row (tie-break: lower index, = jax.lax.top_k) ----------------
#define LT(av,ai,bv,bi) (((av) < (bv)) || ((av) == (bv) && (ai) < (bi)))

__global__ __launch_bounds__(256) void k_topk(
    float* out, int* __restrict__ top_idx, int* __restrict__ counts)
{
  int row = blockIdx.x; int tid = threadIdx.x;
  const f32x2* drow = (const f32x2*)(out + OFF_DIST + (size_t)row * N_EMB);
  float v0 = __builtin_inff(), v1 = __builtin_inff(), v2 = __builtin_inff();
  int   i0 = 0x7fffffff,       i1 = 0x7fffffff,       i2 = 0x7fffffff;
  for (int i = tid; i < N_EMB / 2; i += 256){
    f32x2 dv = drow[i];
    #pragma unroll
    for (int j = 0; j < 2; j++){
      float d = dv[j]; int ii = i * 2 + j;
      if (LT(d, ii, v2, i2)){
        if (LT(d, ii, v1, i1)){
          v2 = v1; i2 = i1;
          if (LT(d, ii, v0, i0)){ v1 = v0; i1 = i0; v0 = d; i0 = ii; }
          else                  { v1 = d;  i1 = ii; }
        } else { v2 = d; i2 = ii; }
      }
    }
  }
  // wave butterfly merge of sorted triples
  #pragma unroll
  for (int off = 1; off < 64; off <<= 1){
    float b0 = __shfl_xor(v0, off), b1 = __shfl_xor(v1, off), b2 = __shfl_xor(v2, off);
    int   j0 = __shfl_xor(i0, off), j1 = __shfl_xor(i1, off), j2 = __shfl_xor(i2, off);
    float a0 = v0, a1 = v1, a2 = v2; int x0 = i0, x1 = i1, x2 = i2;
    float r0, r1, r2; int s0, s1, s2;
    if (LT(a0, x0, b0, j0)){ r0 = a0; s0 = x0; a0 = a1; x0 = x1; a1 = a2; x1 = x2; a2 = __builtin_inff(); x2 = 0x7fffffff; }
    else                   { r0 = b0; s0 = j0; b0 = b1; j0 = j1; b1 = b2; j1 = j2; b2 = __builtin_inff(); j2 = 0x7fffffff; }
    if (LT(a0, x0, b0, j0)){ r1 = a0; s1 = x0; a0 = a1; x0 = x1; a1 = a2; x1 = x2; a2 = __builtin_inff(); x2 = 0x7fffffff; }
    else                   { r1 = b0; s1 = j0; b0 = b1; j0 = j1; b1 = b2; j1 = j2; b2 = __builtin_inff(); j2 = 0x7fffffff; }
    if (LT(a0, x0, b0, j0)){ r2 = a0; s2 = x0; }
    else                   { r2 = b0; s2 = j0; }
    v0 = r0; i0 = s0; v1 = r1; i1 = s1; v2 = r2; i2 = s2;
  }
  __shared__ float swv[4][3]; __shared__ int swi[4][3];
  int lane = tid & 63, wid = tid >> 6;
  if (lane == 0){
    swv[wid][0] = v0; swv[wid][1] = v1; swv[wid][2] = v2;
    swi[wid][0] = i0; swi[wid][1] = i1; swi[wid][2] = i2;
  }
  __syncthreads();
  if (tid == 0){
    for (int wq = 1; wq < 4; wq++){
      for (int t = 0; t < 3; t++){
        float d = swv[wq][t]; int i = swi[wq][t];
        if (LT(d, i, v2, i2)){
          if (LT(d, i, v1, i1)){
            v2 = v1; i2 = i1;
            if (LT(d, i, v0, i0)){ v1 = v0; i1 = i0; v0 = d; i0 = i; }
            else                 { v1 = d;  i1 = i; }
          } else { v2 = d; i2 = i; }
        }
      }
    }
    out[OFF_IDX + (size_t)row * 3 + 0] = (float)i0;
    out[OFF_IDX + (size_t)row * 3 + 1] = (float)i1;
    out[OFF_IDX + (size_t)row * 3 + 2] = (float)i2;
    top_idx[row * 3 + 0] = i0; top_idx[row * 3 + 1] = i1; top_idx[row * 3 + 2] = i2;
    atomicAdd(&counts[i0], 1); atomicAdd(&counts[i1], 1); atomicAdd(&counts[i2], 1);
  }
}

// ---------------- gather + straight-through + loss partials ----------------
__global__ __launch_bounds__(256) void k_quant(
    const float* __restrict__ X, const float* __restrict__ E,
    const int* __restrict__ top_idx, float* __restrict__ out,
    float* __restrict__ partials)
{
  int row = blockIdx.x; int c = threadIdx.x;
  float x = X[(size_t)row * C_DIM + c];
  float lsum = 0.f;
  #pragma unroll
  for (int t = 0; t < 3; t++){
    int idx = top_idx[row * 3 + t];
    float e = E[(size_t)idx * C_DIM + c];
    float diff = e - x;
    out[OFF_Q + ((size_t)row * 3 + t) * C_DIM + c] = x + diff; // literal STE formula
    lsum += diff * diff;
  }
  __shared__ float red[256];
  red[c] = lsum; __syncthreads();
  for (int s = 128; s > 0; s >>= 1){ if (c < s) red[c] += red[c + s]; __syncthreads(); }
  if (c == 0) partials[row] = red[0];
}

// ---------------- scalars: loss + perplexity ----------------
__global__ __launch_bounds__(256) void k_final(
    const float* __restrict__ partials, const int* __restrict__ counts,
    float* __restrict__ out)
{
  int t = threadIdx.x;
  float ls = 0.f;
  for (int i = t; i < N_ROWS; i += 256) ls += partials[i];
  float es = 0.f;
  for (int i = t; i < N_EMB; i += 256){
    float p = (float)counts[i] * (1.0f / 16384.0f);
    es += p * logf(p + 1e-10f);
  }
  __shared__ float r1[256], r2[256];
  r1[t] = ls; r2[t] = es; __syncthreads();
  for (int s = 128; s > 0; s >>= 1){
    if (t < s){ r1[t] += r1[t + s]; r2[t] += r2[t + s]; }
    __syncthreads();
  }
  if (t == 0){
    out[OFF_LOSS] = 0.25f * r1[0] / 12582912.0f;
    out[OFF_PERP] = expf(-r2[0]);
  }
}

extern "C" void kernel_launch(void* const* d_in, const int* in_sizes, int n_in,
                              void* d_out, int out_size, void* d_ws, size_t ws_size,
                              hipStream_t stream)
{
  const float* X = (const float*)d_in[0];
  const float* E = (const float*)d_in[1];
  float* out = (float*)d_out;
  char* ws = (char*)d_ws;
  // ws layout (bytes)
  short* XT       = (short*)(ws + 0);          // 16384*768*2 = 25165824 (K-chunk-major)
  short* ET       = (short*)(ws + 25165824);   // 8192*768*2  = 12582912 (K-chunk-major)
  float* xnorm    = (float*)(ws + 37748736);   // 65536
  float* enorm    = (float*)(ws + 37814272);   // 32768
  int*   top_idx  = (int*)  (ws + 37847040);   // 196608
  int*   counts   = (int*)  (ws + 38043648);   // 32768
  float* partials = (float*)(ws + 38076416);   // 65536  (total ~38.1 MB)

  hipMemsetAsync(counts, 0, N_EMB * sizeof(int), stream);
  k_prep<<<N_ROWS + N_EMB, 256, 0, stream>>>(X, E, XT, ET, xnorm, enorm);
  k_gemm<<<4096, 256, 0, stream>>>(XT, ET, xnorm, enorm, out);
  k_topk<<<N_ROWS, 256, 0, stream>>>(out, top_idx, counts);
  k_quant<<<N_ROWS, 256, 0, stream>>>(X, E, top_idx, out, partials);
  k_final<<<1, 256, 0, stream>>>(partials, counts, out);
}